// Round 6
// baseline (8461.068 us; speedup 1.0000x reference)
//
#include <hip/hip_runtime.h>

typedef _Float16 v8h __attribute__((ext_vector_type(8)));
typedef _Float16 v4h __attribute__((ext_vector_type(4)));
typedef float    v4f __attribute__((ext_vector_type(4)));

#define HID  100
#define TENC 4096
#define TDEC 4096
#define NCLS 6
#define NTHR 448   // 7 waves

__device__ __forceinline__ float sigm(float v)  { return __builtin_amdgcn_rcpf(1.0f + __expf(-v)); }
__device__ __forceinline__ float tanh_(float v) { return 1.0f - 2.0f * __builtin_amdgcn_rcpf(1.0f + __expf(2.0f * v)); }

// Persistent single-workgroup LSTM, MFMA edition.
// Step = [Whh | bias | Wih]_perm (400x128, f16) @ h~ (128, f16) via
// v_mfma_f32_16x16x32_f16. Rows permuted to 4*cell+gate; k augmented:
// k<100 = Whh, k=100 = bih+bhh (h~[100]=1), k=101.. = Wih cols (h~=x or y),
// rest zero. 7 waves x 4 M-tiles x 4 K-tiles; A-frags (weights) = 64 VGPRs
// per lane, mfma operands (AGPR-spill is free on gfx950's unified file).
// C/D layout (m89): owner lanes (lane&15==0) get col 0: lane q<<4 reg r =
// row 4q+r of the tile = cell 16w+4mt+q, gate r -> owner holds all 4 gates
// of its cell, activates, owns c, writes h f16 to LDS. ONE barrier/step.
// R2-R5 post-mortem: any VALU/DS formulation floors at ~1400 cyc/step
// (57% VALU-busy on the CU); mfma moves the 40k MACs+reduction to the
// matrix pipe and cuts DS ops/wave from ~36 to ~9.
__global__ __launch_bounds__(NTHR, 1)
void lstm_rec(const float* __restrict__ x,      // [TENC*3]
              const int*   __restrict__ y,      // [TDEC]
              const float* __restrict__ eWih,   // [400*3]
              const float* __restrict__ eWhh,   // [400*HID]
              const float* __restrict__ ebih,
              const float* __restrict__ ebhh,
              const float* __restrict__ dWih,   // [400]
              const float* __restrict__ dWhh,
              const float* __restrict__ dbih,
              const float* __restrict__ dbhh,
              float* __restrict__ hsto)         // [(TDEC-1)*HID] decoder h history
{
    __shared__ __align__(16) _Float16 hbuf[2][128];  // h~ double-buffered: [0..99]=h, [100]=1, [101..103]=x/y, rest 0

    const int  t  = threadIdx.x;
    const int  w  = t >> 6;
    const int  l  = t & 63;
    const int  q  = l >> 4;        // quad
    const int  m  = l & 15;        // within-tile row for A, col for C/D
    const bool own    = (m == 0);  // B-loader + C-owner lanes
    const bool writer = (w == 6 && l == 1);   // x/y slot writer (idle lane)

    v8h  afrag[16];                // [mt*4+kt] A-fragments (weights) — loop-invariant
    v8h  bfrag[4];                 // [kt] h~ fragments; nonzero only on own lanes
    float cst[4]   = {0.f, 0.f, 0.f, 0.f};   // cell state, one per M-tile
    float hprev[4] = {0.f, 0.f, 0.f, 0.f};   // staged decoder h for hsto

    #pragma unroll
    for (int kt = 0; kt < 4; ++kt) {
        v8h z; 
        #pragma unroll
        for (int j = 0; j < 8; ++j) z[j] = (_Float16)0.0f;
        bfrag[kt] = z;
    }

    // ---- LDS init: zeros, slot 100 = 1 in both parities ----
    if (t < 256) hbuf[t >> 7][t & 127] = (_Float16)(((t & 127) == 100) ? 1.0f : 0.0f);

    // ---- pack A-frags: A[mrow=m][k=q*8+j] per tile ----
    auto packA = [&](const float* Whh, const float* Wih, int wcols,
                     const float* bih, const float* bhh) {
        #pragma unroll
        for (int mt = 0; mt < 4; ++mt) {
            const int  gm   = w * 4 + mt;
            const int  cell = 4 * gm + (m >> 2);
            const int  gate = m & 3;
            const int  row  = cell + gate * HID;
            const bool lv   = (cell < HID);
            #pragma unroll
            for (int kt = 0; kt < 4; ++kt) {
                v8h fr;
                #pragma unroll
                for (int j = 0; j < 8; ++j) {
                    const int k = kt * 32 + q * 8 + j;
                    float v = 0.0f;
                    if (lv) {
                        if (k < HID)            v = Whh[row * HID + k];
                        else if (k == HID)      v = bih[row] + bhh[row];
                        else if (k < HID + 1 + wcols) v = Wih[row * wcols + (k - HID - 1)];
                    }
                    fr[j] = (_Float16)v;
                }
                afrag[mt * 4 + kt] = fr;
            }
        }
    };

    packA(eWhh, eWih, 3, ebih, ebhh);
    __syncthreads();
    if (writer)   // x for step 0 into parity-0 buffer
        *(v4h*)&hbuf[0][HID] = (v4h){(_Float16)1.0f, (_Float16)x[0], (_Float16)x[1], (_Float16)x[2]};
    float xl0 = 0.f, xl1 = 0.f, xl2 = 0.f;
    if (writer) { xl0 = x[3]; xl1 = x[4]; xl2 = x[5]; }   // x for step 1
    __syncthreads();

    int p = 0;

    // ================ encoder: 4096 steps ================
    for (int s = 0; s < TENC; ++s) {
        if (own) {
            #pragma unroll
            for (int kt = 0; kt < 4; ++kt)
                bfrag[kt] = *(const v8h*)&hbuf[p][kt * 32 + q * 8];
        }
        v4f acc[4];
        #pragma unroll
        for (int mt = 0; mt < 4; ++mt) { acc[mt][0]=0.f; acc[mt][1]=0.f; acc[mt][2]=0.f; acc[mt][3]=0.f; }
        #pragma unroll
        for (int kt = 0; kt < 4; ++kt)
            #pragma unroll
            for (int mt = 0; mt < 4; ++mt)
                acc[mt] = __builtin_amdgcn_mfma_f32_16x16x32_f16(afrag[mt * 4 + kt], bfrag[kt], acc[mt], 0, 0, 0);

        if (writer) {   // publish x for step s+1 into the s+1 buffer
            *(v4h*)&hbuf[p ^ 1][HID] = (v4h){(_Float16)1.0f, (_Float16)xl0, (_Float16)xl1, (_Float16)xl2};
            if (s + 2 < TENC) { xl0 = x[3*s+6]; xl1 = x[3*s+7]; xl2 = x[3*s+8]; }
        }
        if (own) {
            #pragma unroll
            for (int mt = 0; mt < 4; ++mt) {
                const int cell = 16 * w + 4 * mt + q;
                if (cell < HID) {
                    const float fi = sigm(acc[mt][0]);
                    const float ff = sigm(acc[mt][1]);
                    const float fg = tanh_(acc[mt][2]);
                    const float fo = sigm(acc[mt][3]);
                    cst[mt] = ff * cst[mt] + fi * fg;
                    const float hn = fo * tanh_(cst[mt]);
                    hbuf[p ^ 1][cell] = (_Float16)hn;
                }
            }
        }
        __syncthreads();
        p ^= 1;
    }

    // ================ swap to decoder weights ================
    packA(dWhh, dWih, 1, dbih, dbhh);
    if (writer)   // decoder input for step 0 = y[0]; also zeroes stale x slots 102/103
        *(v4h*)&hbuf[p][HID] = (v4h){(_Float16)1.0f, (_Float16)(float)y[0], (_Float16)0.0f, (_Float16)0.0f};
    float ynext = 0.f;
    if (writer) ynext = (float)y[1];
    __syncthreads();

    // ================ decoder: 4095 steps (ratio==1 -> teacher-forced) ================
    for (int s = 0; s < TDEC - 1; ++s) {
        // staged hsto store from previous step: issued right after the barrier,
        // so the pre-barrier vmcnt(0) drain at the END of this step hides it.
        if (own && s > 0) {
            #pragma unroll
            for (int mt = 0; mt < 4; ++mt) {
                const int cell = 16 * w + 4 * mt + q;
                if (cell < HID) hsto[(s - 1) * HID + cell] = hprev[mt];
            }
        }
        if (own) {
            #pragma unroll
            for (int kt = 0; kt < 4; ++kt)
                bfrag[kt] = *(const v8h*)&hbuf[p][kt * 32 + q * 8];
        }
        v4f acc[4];
        #pragma unroll
        for (int mt = 0; mt < 4; ++mt) { acc[mt][0]=0.f; acc[mt][1]=0.f; acc[mt][2]=0.f; acc[mt][3]=0.f; }
        #pragma unroll
        for (int kt = 0; kt < 4; ++kt)
            #pragma unroll
            for (int mt = 0; mt < 4; ++mt)
                acc[mt] = __builtin_amdgcn_mfma_f32_16x16x32_f16(afrag[mt * 4 + kt], bfrag[kt], acc[mt], 0, 0, 0);

        if (writer) {   // publish y for step s+1
            *(v4h*)&hbuf[p ^ 1][HID] = (v4h){(_Float16)1.0f, (_Float16)ynext, (_Float16)0.0f, (_Float16)0.0f};
            if (s + 2 < TDEC) ynext = (float)y[s + 2];
        }
        if (own) {
            #pragma unroll
            for (int mt = 0; mt < 4; ++mt) {
                const int cell = 16 * w + 4 * mt + q;
                if (cell < HID) {
                    const float fi = sigm(acc[mt][0]);
                    const float ff = sigm(acc[mt][1]);
                    const float fg = tanh_(acc[mt][2]);
                    const float fo = sigm(acc[mt][3]);
                    cst[mt] = ff * cst[mt] + fi * fg;
                    const float hn = fo * tanh_(cst[mt]);
                    hbuf[p ^ 1][cell] = (_Float16)hn;
                    hprev[mt] = hn;
                }
            }
        }
        __syncthreads();
        p ^= 1;
    }
    // final staged row (s = TDEC-2)
    if (own) {
        #pragma unroll
        for (int mt = 0; mt < 4; ++mt) {
            const int cell = 16 * w + 4 * mt + q;
            if (cell < HID) hsto[(TDEC - 2) * HID + cell] = hprev[mt];
        }
    }
}

// Parallel logits: out[t][r] = linW[r] . h_t + linb[r], last row zeroed.
__global__ __launch_bounds__(256)
void logits_k(const float* __restrict__ hsto, const float* __restrict__ linW,
              const float* __restrict__ linb, float* __restrict__ out)
{
    const int idx = blockIdx.x * 256 + threadIdx.x;
    if (idx >= TDEC * NCLS) return;
    const int tt = idx / NCLS;
    const int r  = idx % NCLS;
    if (tt >= TDEC - 1) { out[idx] = 0.0f; return; }
    const float* h  = hsto + tt * HID;
    const float* wr = linW + r * HID;
    float a = linb[r];
    #pragma unroll 4
    for (int k = 0; k < HID; ++k) a += wr[k] * h[k];
    out[idx] = a;
}

extern "C" void kernel_launch(void* const* d_in, const int* in_sizes, int n_in,
                              void* d_out, int out_size, void* d_ws, size_t ws_size,
                              hipStream_t stream)
{
    const float* x    = (const float*)d_in[0];
    const int*   y    = (const int*)  d_in[1];
    const float* eWih = (const float*)d_in[2];
    const float* eWhh = (const float*)d_in[3];
    const float* ebih = (const float*)d_in[4];
    const float* ebhh = (const float*)d_in[5];
    const float* dWih = (const float*)d_in[6];
    const float* dWhh = (const float*)d_in[7];
    const float* dbih = (const float*)d_in[8];
    const float* dbhh = (const float*)d_in[9];
    const float* linW = (const float*)d_in[10];
    const float* linb = (const float*)d_in[11];
    float* out  = (float*)d_out;
    float* hsto = (float*)d_ws;   // (TDEC-1)*HID*4 = 1.64 MB scratch

    lstm_rec<<<dim3(1), dim3(NTHR), 0, stream>>>(
        x, y, eWih, eWhh, ebih, ebhh, dWih, dWhh, dbih, dbhh, hsto);

    const int nout = TDEC * NCLS;
    logits_k<<<dim3((nout + 255) / 256), dim3(256), 0, stream>>>(hsto, linW, linb, out);
}

// Round 7
// 4154.197 us; speedup vs baseline: 2.0368x; 2.0368x over previous
//
#include <hip/hip_runtime.h>

typedef _Float16 h2_t __attribute__((ext_vector_type(2)));

#define HID  100
#define TENC 4096
#define TDEC 4096
#define NCLS 6
#define NTHR 256   // 4 waves, one per SIMD

__device__ __forceinline__ float sigm(float v)  { return __builtin_amdgcn_rcpf(1.0f + __expf(-v)); }
__device__ __forceinline__ float tanh_(float v) { return 1.0f - 2.0f * __builtin_amdgcn_rcpf(1.0f + __expf(2.0f * v)); }

// lgkm-only barrier: does NOT drain vmcnt, so global stores/loads stay in
// flight across steps (unlike __syncthreads, which emits s_waitcnt vmcnt(0)
// and was draining the hsto store + x prefetch EVERY step in R2-R5).
#define SYNC_LDS() asm volatile("s_waitcnt lgkmcnt(0)\n\ts_barrier" ::: "memory")

__device__ __forceinline__ float packh2(float a, float b) {
    h2_t p; p[0] = (_Float16)a; p[1] = (_Float16)b;
    return __builtin_bit_cast(float, p);
}

// Persistent single-workgroup LSTM, v4. Model from R2-R6 post-mortems:
// step = DS-pipe occupancy + barrier drain + serial chain. This version
// minimizes all three: 4 waves (min that covers 100 cells at 2 lanes/cell),
// lane=(ci<32, half), cell=w*32+ci. Lane holds ALL 4 gate rows of its cell
// over its k-half: 4x25 packed-f16 pairs = 100 VGPRs (R4 proved ~112 stays
// resident). Per step/wave: 7 ds_read (h half, 100B) + 1 ds_read (x/y) +
// 4 shfl_xor(32) k-reduction + 1 ds_write = ~13 DS ops (R5 had 16 on 7
// waves). ONE lgkm-only barrier per step. x/y staged in LDS at setup ->
// zero global loads in loop; hsto stores by half-1 lanes, never fenced.
__global__ __launch_bounds__(NTHR, 1)
void lstm_rec(const float* __restrict__ x,      // [TENC*3]
              const int*   __restrict__ y,      // [TDEC]
              const float* __restrict__ eWih,   // [400*3]
              const float* __restrict__ eWhh,   // [400*HID]
              const float* __restrict__ ebih,
              const float* __restrict__ ebhh,
              const float* __restrict__ dWih,   // [400]
              const float* __restrict__ dWhh,
              const float* __restrict__ dbih,
              const float* __restrict__ dbhh,
              float* __restrict__ hsto)         // [(TDEC-1)*HID] decoder h history
{
    __shared__ __align__(16) _Float16 hbuf[2][2][64];  // [parity][k-half][50 used of 64]
    __shared__ __align__(8)  uint2    xst[TENC];       // packed f16: {x0,x1},{x2,1}
    __shared__               unsigned yst[TDEC];       // packed f16: {yf,0}

    const int  t    = threadIdx.x;
    const int  w    = t >> 6;
    const int  l    = t & 63;
    const int  ci   = l & 31;
    const int  half = l >> 5;
    const int  cell = w * 32 + ci;
    const bool live = (cell < HID);
    const int  k0   = half * 50;

    // ---- stage x (f16 pairs) and y (f16) into LDS; zero h buffers ----
    for (int i = t; i < TENC; i += NTHR) {
        const float a = x[3*i], b = x[3*i+1], cc = x[3*i+2];
        uint2 u;
        u.x = __builtin_bit_cast(unsigned, packh2(a, b));
        u.y = __builtin_bit_cast(unsigned, packh2(cc, 1.0f));
        xst[i] = u;
    }
    for (int i = t; i < TDEC; i += NTHR)
        yst[i] = __builtin_bit_cast(unsigned, packh2((float)y[i], 0.0f));
    if (t < 256) ((_Float16*)hbuf)[t] = (_Float16)0.0f;

    // ---- encoder weights: 4 gates x 25 f16-pairs (k-half) per lane ----
    float wf[4][25];
    float wxp[4][2], bs[4];
    float c = 0.0f;
    #pragma unroll
    for (int r = 0; r < 4; ++r) {
        #pragma unroll
        for (int j = 0; j < 25; ++j) wf[r][j] = 0.0f;
        wxp[r][0] = wxp[r][1] = 0.0f; bs[r] = 0.0f;
    }
    if (live) {
        #pragma unroll
        for (int r = 0; r < 4; ++r) {
            const int row = cell + r * HID;
            #pragma unroll
            for (int j = 0; j < 25; ++j)
                wf[r][j] = packh2(eWhh[row*HID + k0 + 2*j], eWhh[row*HID + k0 + 2*j + 1]);
            if (half == 0) {   // input/bias fed once, pre-reduction
                wxp[r][0] = packh2(eWih[row*3+0], eWih[row*3+1]);
                wxp[r][1] = packh2(eWih[row*3+2], 0.0f);
                bs[r]     = ebih[row] + ebhh[row];
            }
        }
    }
    __syncthreads();   // once, covers staging

    int p = 0;

    // ================ encoder: 4096 steps ================
    for (int s = 0; s < TENC; ++s) {
        const float4* h4 = (const float4*)&hbuf[p][half][0];
        float hp[25];
        #pragma unroll
        for (int j = 0; j < 6; ++j) {      // 6 x ds_read_b128 = 24 pairs
            const float4 v = h4[j];
            hp[4*j+0] = v.x; hp[4*j+1] = v.y; hp[4*j+2] = v.z; hp[4*j+3] = v.w;
        }
        hp[24] = ((const float*)h4)[24];   // 25th pair (b32)

        float a0, a1, a2, a3;
        if (half == 0) {
            const uint2 xp = xst[s];       // b64 broadcast
            const h2_t x0 = __builtin_bit_cast(h2_t, xp.x);
            const h2_t x1 = __builtin_bit_cast(h2_t, xp.y);
            a0 = __builtin_amdgcn_fdot2(__builtin_bit_cast(h2_t, wxp[0][0]), x0,
                 __builtin_amdgcn_fdot2(__builtin_bit_cast(h2_t, wxp[0][1]), x1, bs[0], false), false);
            a1 = __builtin_amdgcn_fdot2(__builtin_bit_cast(h2_t, wxp[1][0]), x0,
                 __builtin_amdgcn_fdot2(__builtin_bit_cast(h2_t, wxp[1][1]), x1, bs[1], false), false);
            a2 = __builtin_amdgcn_fdot2(__builtin_bit_cast(h2_t, wxp[2][0]), x0,
                 __builtin_amdgcn_fdot2(__builtin_bit_cast(h2_t, wxp[2][1]), x1, bs[2], false), false);
            a3 = __builtin_amdgcn_fdot2(__builtin_bit_cast(h2_t, wxp[3][0]), x0,
                 __builtin_amdgcn_fdot2(__builtin_bit_cast(h2_t, wxp[3][1]), x1, bs[3], false), false);
        } else { a0 = a1 = a2 = a3 = 0.0f; }

        #pragma unroll
        for (int j = 0; j < 25; ++j) {
            const h2_t hh = __builtin_bit_cast(h2_t, hp[j]);
            a0 = __builtin_amdgcn_fdot2(__builtin_bit_cast(h2_t, wf[0][j]), hh, a0, false);
            a1 = __builtin_amdgcn_fdot2(__builtin_bit_cast(h2_t, wf[1][j]), hh, a1, false);
            a2 = __builtin_amdgcn_fdot2(__builtin_bit_cast(h2_t, wf[2][j]), hh, a2, false);
            a3 = __builtin_amdgcn_fdot2(__builtin_bit_cast(h2_t, wf[3][j]), hh, a3, false);
        }
        a0 += __shfl_xor(a0, 32);          // k-reduction: halves are 32 apart
        a1 += __shfl_xor(a1, 32);
        a2 += __shfl_xor(a2, 32);
        a3 += __shfl_xor(a3, 32);

        const float fi = sigm(a0), ff = sigm(a1), fg = tanh_(a2), fo = sigm(a3);
        c = ff * c + fi * fg;              // replicated in both halves
        const float hn = fo * tanh_(c);
        if (half == 0 && live) {
            const int hh2 = (cell < 50) ? 0 : 1;
            hbuf[p ^ 1][hh2][cell - 50*hh2] = (_Float16)hn;
        }
        SYNC_LDS();
        p ^= 1;
    }

    // ================ swap to decoder weights ================
    float wdp[4], bsd[4];
    #pragma unroll
    for (int r = 0; r < 4; ++r) { wdp[r] = 0.0f; bsd[r] = 0.0f; }
    if (live) {
        #pragma unroll
        for (int r = 0; r < 4; ++r) {
            const int row = cell + r * HID;
            #pragma unroll
            for (int j = 0; j < 25; ++j)
                wf[r][j] = packh2(dWhh[row*HID + k0 + 2*j], dWhh[row*HID + k0 + 2*j + 1]);
            if (half == 0) {
                wdp[r] = packh2(dWih[row], 0.0f);
                bsd[r] = dbih[row] + dbhh[row];
            }
        }
    }

    // ================ decoder: 4095 steps (ratio==1 -> teacher-forced) ================
    for (int s = 0; s < TDEC - 1; ++s) {
        const float4* h4 = (const float4*)&hbuf[p][half][0];
        float hp[25];
        #pragma unroll
        for (int j = 0; j < 6; ++j) {
            const float4 v = h4[j];
            hp[4*j+0] = v.x; hp[4*j+1] = v.y; hp[4*j+2] = v.z; hp[4*j+3] = v.w;
        }
        hp[24] = ((const float*)h4)[24];

        float a0, a1, a2, a3;
        if (half == 0) {
            const h2_t yp = __builtin_bit_cast(h2_t, yst[s]);   // {yf, 0}
            a0 = __builtin_amdgcn_fdot2(__builtin_bit_cast(h2_t, wdp[0]), yp, bsd[0], false);
            a1 = __builtin_amdgcn_fdot2(__builtin_bit_cast(h2_t, wdp[1]), yp, bsd[1], false);
            a2 = __builtin_amdgcn_fdot2(__builtin_bit_cast(h2_t, wdp[2]), yp, bsd[2], false);
            a3 = __builtin_amdgcn_fdot2(__builtin_bit_cast(h2_t, wdp[3]), yp, bsd[3], false);
        } else { a0 = a1 = a2 = a3 = 0.0f; }

        #pragma unroll
        for (int j = 0; j < 25; ++j) {
            const h2_t hh = __builtin_bit_cast(h2_t, hp[j]);
            a0 = __builtin_amdgcn_fdot2(__builtin_bit_cast(h2_t, wf[0][j]), hh, a0, false);
            a1 = __builtin_amdgcn_fdot2(__builtin_bit_cast(h2_t, wf[1][j]), hh, a1, false);
            a2 = __builtin_amdgcn_fdot2(__builtin_bit_cast(h2_t, wf[2][j]), hh, a2, false);
            a3 = __builtin_amdgcn_fdot2(__builtin_bit_cast(h2_t, wf[3][j]), hh, a3, false);
        }
        a0 += __shfl_xor(a0, 32);
        a1 += __shfl_xor(a1, 32);
        a2 += __shfl_xor(a2, 32);
        a3 += __shfl_xor(a3, 32);

        const float fi = sigm(a0), ff = sigm(a1), fg = tanh_(a2), fo = sigm(a3);
        c = ff * c + fi * fg;
        const float hn = fo * tanh_(c);
        if (live) {
            if (half == 0) {
                const int hh2 = (cell < 50) ? 0 : 1;
                hbuf[p ^ 1][hh2][cell - 50*hh2] = (_Float16)hn;
            } else {
                hsto[s * HID + cell] = hn;     // global store, never fenced in-loop
            }
        }
        SYNC_LDS();
        p ^= 1;
    }
    // kernel end-of-dispatch drains the hsto stores before logits_k launches
}

// Parallel logits: out[t][r] = linW[r] . h_t + linb[r], last row zeroed.
__global__ __launch_bounds__(256)
void logits_k(const float* __restrict__ hsto, const float* __restrict__ linW,
              const float* __restrict__ linb, float* __restrict__ out)
{
    const int idx = blockIdx.x * 256 + threadIdx.x;
    if (idx >= TDEC * NCLS) return;
    const int tt = idx / NCLS;
    const int r  = idx % NCLS;
    if (tt >= TDEC - 1) { out[idx] = 0.0f; return; }
    const float* h  = hsto + tt * HID;
    const float* wr = linW + r * HID;
    float a = linb[r];
    #pragma unroll 4
    for (int k = 0; k < HID; ++k) a += wr[k] * h[k];
    out[idx] = a;
}

extern "C" void kernel_launch(void* const* d_in, const int* in_sizes, int n_in,
                              void* d_out, int out_size, void* d_ws, size_t ws_size,
                              hipStream_t stream)
{
    const float* x    = (const float*)d_in[0];
    const int*   y    = (const int*)  d_in[1];
    const float* eWih = (const float*)d_in[2];
    const float* eWhh = (const float*)d_in[3];
    const float* ebih = (const float*)d_in[4];
    const float* ebhh = (const float*)d_in[5];
    const float* dWih = (const float*)d_in[6];
    const float* dWhh = (const float*)d_in[7];
    const float* dbih = (const float*)d_in[8];
    const float* dbhh = (const float*)d_in[9];
    const float* linW = (const float*)d_in[10];
    const float* linb = (const float*)d_in[11];
    float* out  = (float*)d_out;
    float* hsto = (float*)d_ws;   // (TDEC-1)*HID*4 = 1.64 MB scratch

    lstm_rec<<<dim3(1), dim3(NTHR), 0, stream>>>(
        x, y, eWih, eWhh, ebih, ebhh, dWih, dWhh, dbih, dbhh, hsto);

    const int nout = TDEC * NCLS;
    logits_k<<<dim3((nout + 255) / 256), dim3(256), 0, stream>>>(hsto, linW, linb, out);
}